// Round 3
// baseline (115.157 us; speedup 1.0000x reference)
//
#include <hip/hip_runtime.h>
#include <hip/hip_fp16.h>

#define HIDDEN 32
#define NOUT 9
// combined y row: [src: 9 fp16 + pad, dst: 9 fp16 + pad] = 10 dwords = 40 B
#define ROWDW 10

__device__ __forceinline__ float fast_tanh(float v) {
    float e = __expf(2.0f * v);
    return 1.0f - __fdividef(2.0f, e + 1.0f);
}

__device__ __forceinline__ unsigned pack2(float a, float b) {
    unsigned lo = __half_as_ushort(__float2half(a));
    unsigned hi = __half_as_ushort(__float2half(b));
    return lo | (hi << 16);
}

// ---------------- pass 1: y[i] = [W[:, :32]@x_i , W[:, 32:]@x_i] fp16 -------
__global__ __launch_bounds__(256) void precompute_kernel(
    const float* __restrict__ x,   // [NR, 32]
    const float* __restrict__ W,   // [9, 64]
    unsigned*    __restrict__ yt,  // [NR, 10] dwords
    int NR)
{
    __shared__ float XL[256 * 33];      // 256 rows, stride 33 (bank-conflict-free)
    __shared__ float Wl[NOUT * 64];
    for (int i = threadIdx.x; i < NOUT * 64; i += 256) Wl[i] = W[i];

    const int base = blockIdx.x * 256;
    const float4* Xv = reinterpret_cast<const float4*>(x);
    #pragma unroll
    for (int i = 0; i < 8; ++i) {
        int f   = i * 256 + threadIdx.x;     // float4 index within block tile
        int row = f >> 3, ch = f & 7;
        float4 v = make_float4(0.f, 0.f, 0.f, 0.f);
        if (base + row < NR) v = Xv[(size_t)(base + row) * 8 + ch];
        float* p = &XL[row * 33 + ch * 4];
        p[0] = v.x; p[1] = v.y; p[2] = v.z; p[3] = v.w;
    }
    __syncthreads();

    const int row = base + threadIdx.x;
    if (row >= NR) return;

    float ys[NOUT], yd[NOUT];
    #pragma unroll
    for (int j = 0; j < NOUT; ++j) { ys[j] = 0.f; yd[j] = 0.f; }

    const float* xr = &XL[threadIdx.x * 33];
    #pragma unroll
    for (int c = 0; c < 32; ++c) {
        float xv = xr[c];
        #pragma unroll
        for (int j = 0; j < NOUT; ++j) {
            ys[j] += xv * Wl[j * 64 + c];
            yd[j] += xv * Wl[j * 64 + 32 + c];
        }
    }

    unsigned* orow = yt + (size_t)row * ROWDW;
    orow[0] = pack2(ys[0], ys[1]);
    orow[1] = pack2(ys[2], ys[3]);
    orow[2] = pack2(ys[4], ys[5]);
    orow[3] = pack2(ys[6], ys[7]);
    orow[4] = pack2(ys[8], 0.f);
    orow[5] = pack2(yd[0], yd[1]);
    orow[6] = pack2(yd[2], yd[3]);
    orow[7] = pack2(yd[4], yd[5]);
    orow[8] = pack2(yd[6], yd[7]);
    orow[9] = pack2(yd[8], 0.f);
}

// ---------------- pass 2: one lane per group, 30 dword gathers --------------
struct U5 { unsigned a, b, c, d, e; };
__device__ __forceinline__ U5 ld5(const unsigned* p) {
    U5 r; r.a = p[0]; r.b = p[1]; r.c = p[2]; r.d = p[3]; r.e = p[4]; return r;
}
__device__ __forceinline__ void acc9(float* acc, U5 v) {
    float2 f;
    f = __half22float2(*reinterpret_cast<__half2*>(&v.a)); acc[0] += f.x; acc[1] += f.y;
    f = __half22float2(*reinterpret_cast<__half2*>(&v.b)); acc[2] += f.x; acc[3] += f.y;
    f = __half22float2(*reinterpret_cast<__half2*>(&v.c)); acc[4] += f.x; acc[5] += f.y;
    f = __half22float2(*reinterpret_cast<__half2*>(&v.d)); acc[6] += f.x; acc[7] += f.y;
    f = __half22float2(*reinterpret_cast<__half2*>(&v.e)); acc[8] += f.x;
}

__global__ __launch_bounds__(256) void gather_kernel(
    const unsigned* __restrict__ yt,  // [NR, 10] dwords
    const int*      __restrict__ ei,  // [2, E]
    float*          __restrict__ out, // [G, 9]
    int G, int E)
{
    int g = blockIdx.x * 256 + threadIdx.x;
    if (g >= G) return;

    const int* sp = ei + 3 * (size_t)g;
    const int* dp = ei + (size_t)E + 3 * (size_t)g;
    int s0 = sp[0], s1 = sp[1], s2 = sp[2];
    int d0 = dp[0], d1 = dp[1], d2 = dp[2];

    // all 30 gathers issued up-front (compiler hoists: no aliasing via restrict)
    U5 v0 = ld5(yt + (size_t)s0 * ROWDW);
    U5 v1 = ld5(yt + (size_t)s1 * ROWDW);
    U5 v2 = ld5(yt + (size_t)s2 * ROWDW);
    U5 v3 = ld5(yt + (size_t)d0 * ROWDW + 5);
    U5 v4 = ld5(yt + (size_t)d1 * ROWDW + 5);
    U5 v5 = ld5(yt + (size_t)d2 * ROWDW + 5);

    float acc[NOUT];
    #pragma unroll
    for (int j = 0; j < NOUT; ++j) acc[j] = 0.f;
    acc9(acc, v0); acc9(acc, v1); acc9(acc, v2);
    acc9(acc, v3); acc9(acc, v4); acc9(acc, v5);

    float* o = out + (size_t)g * 9;
    #pragma unroll
    for (int j = 0; j < NOUT; ++j) o[j] = fast_tanh(acc[j]);
}

// ---------------- fallback (round-2 kernel) if ws too small -----------------
__device__ __forceinline__ float dot4(float4 a, float4 b) {
    return a.x * b.x + a.y * b.y + a.z * b.z + a.w * b.w;
}
__global__ __launch_bounds__(256) void sheaf_fallback(
    const float* __restrict__ x, const int* __restrict__ edge_index,
    const float* __restrict__ W, float* __restrict__ out, int G, int E)
{
    __shared__ float Wlds[NOUT * 64];
    for (int i = threadIdx.x; i < NOUT * 64; i += 256) Wlds[i] = W[i];
    __syncthreads();
    const int l = threadIdx.x & 7;
    const int s = (blockIdx.x * 256 + threadIdx.x) >> 3;
    const int g0 = 2 * s, g1 = 2 * s + 1;
    if (g0 >= G) return;
    const bool has1 = (g1 < G);
    const float4* Xv = reinterpret_cast<const float4*>(x);
    const float4* Wv = reinterpret_cast<const float4*>(Wlds);
    const int* sp = edge_index + 3 * g0;
    const int* dp = edge_index + E + 3 * g0;
    int s0 = sp[0], s1 = sp[1], s2 = sp[2], d0 = dp[0], d1 = dp[1], d2 = dp[2];
    int s3 = 0, s4 = 0, s5 = 0, d3 = 0, d4 = 0, d5 = 0;
    if (has1) { s3 = sp[3]; s4 = sp[4]; s5 = sp[5]; d3 = dp[3]; d4 = dp[4]; d5 = dp[5]; }
    float4 a0 = Xv[s0 * 8 + l], a1 = Xv[s1 * 8 + l], a2 = Xv[s2 * 8 + l];
    float4 b0 = Xv[d0 * 8 + l], b1 = Xv[d1 * 8 + l], b2 = Xv[d2 * 8 + l];
    float4 a3 = Xv[s3 * 8 + l], a4 = Xv[s4 * 8 + l], a5 = Xv[s5 * 8 + l];
    float4 b3 = Xv[d3 * 8 + l], b4 = Xv[d4 * 8 + l], b5 = Xv[d5 * 8 + l];
    float4 xs0, xd0, xs1, xd1;
    xs0.x = a0.x + a1.x + a2.x; xs0.y = a0.y + a1.y + a2.y;
    xs0.z = a0.z + a1.z + a2.z; xs0.w = a0.w + a1.w + a2.w;
    xd0.x = b0.x + b1.x + b2.x; xd0.y = b0.y + b1.y + b2.y;
    xd0.z = b0.z + b1.z + b2.z; xd0.w = b0.w + b1.w + b2.w;
    xs1.x = a3.x + a4.x + a5.x; xs1.y = a3.y + a4.y + a5.y;
    xs1.z = a3.z + a4.z + a5.z; xs1.w = a3.w + a4.w + a5.w;
    xd1.x = b3.x + b4.x + b5.x; xd1.y = b3.y + b4.y + b5.y;
    xd1.z = b3.z + b4.z + b5.z; xd1.w = b3.w + b4.w + b5.w;
    float my0 = 0.f, ex0 = 0.f, my1 = 0.f, ex1 = 0.f;
    #pragma unroll
    for (int j = 0; j < NOUT; ++j) {
        float4 ws = Wv[j * 16 + l];
        float4 wd = Wv[j * 16 + 8 + l];
        float t0 = dot4(xs0, ws) + dot4(xd0, wd);
        float t1 = dot4(xs1, ws) + dot4(xd1, wd);
        t0 += __shfl_xor(t0, 1); t1 += __shfl_xor(t1, 1);
        t0 += __shfl_xor(t0, 2); t1 += __shfl_xor(t1, 2);
        t0 += __shfl_xor(t0, 4); t1 += __shfl_xor(t1, 4);
        if (j < 8) { if (l == j) { my0 = t0; my1 = t1; } }
        else { ex0 = t0; ex1 = t1; }
    }
    out[g0 * 9 + l] = fast_tanh(my0);
    if (l == 0) out[g0 * 9 + 8] = fast_tanh(ex0);
    if (has1) {
        out[g1 * 9 + l] = fast_tanh(my1);
        if (l == 0) out[g1 * 9 + 8] = fast_tanh(ex1);
    }
}

extern "C" void kernel_launch(void* const* d_in, const int* in_sizes, int n_in,
                              void* d_out, int out_size, void* d_ws, size_t ws_size,
                              hipStream_t stream) {
    const float* x   = (const float*)d_in[0];
    const int*   ei  = (const int*)d_in[1];
    const float* W   = (const float*)d_in[2];
    float*       out = (float*)d_out;

    const int NR = in_sizes[0] / HIDDEN;  // 300,000
    const int E  = in_sizes[1] / 2;       // 3,000,000
    const int G  = E / 3;                 // 1,000,000

    const size_t tab_bytes = (size_t)NR * ROWDW * 4;  // 12 MB
    if (ws_size >= tab_bytes) {
        unsigned* yt = (unsigned*)d_ws;
        hipLaunchKernelGGL(precompute_kernel, dim3((NR + 255) / 256), dim3(256),
                           0, stream, x, W, yt, NR);
        hipLaunchKernelGGL(gather_kernel, dim3((G + 255) / 256), dim3(256),
                           0, stream, yt, ei, out, G, E);
    } else {
        const int subwaves = (G + 1) / 2;
        const int blocks   = (subwaves + 31) / 32;
        hipLaunchKernelGGL(sheaf_fallback, dim3(blocks), dim3(256), 0, stream,
                           x, ei, W, out, G, E);
    }
}